// Round 3
// baseline (67.051 us; speedup 1.0000x reference)
//
#include <hip/hip_runtime.h>

#define DD 2048
#define MHH 32

// One-block prep: SA = sum_m Wm1[0,m]*Wm2[m], SB = sum_m Wm1[1,m]*Wm2[m],
// K1 = sum_m bm1[m]*Wm2[m], K2 = sum_m Wm1[2,m]*Wm2[m].
__global__ void prep_k(const float* __restrict__ Wm1, const float* __restrict__ bm1,
                       const float* __restrict__ Wm2, float* __restrict__ sums) {
    const int lane = threadIdx.x;      // 64 threads, lanes 0..31 active
    float sa = 0.f, sb = 0.f, k1 = 0.f, k2 = 0.f;
    if (lane < MHH) {
        const float v2 = Wm2[lane];
        sa = Wm1[lane] * v2;
        sb = Wm1[MHH + lane] * v2;
        k2 = Wm1[2 * MHH + lane] * v2;
        k1 = bm1[lane] * v2;
    }
#pragma unroll
    for (int off = 16; off > 0; off >>= 1) {
        sa += __shfl_down(sa, off, 64);
        sb += __shfl_down(sb, off, 64);
        k1 += __shfl_down(k1, off, 64);
        k2 += __shfl_down(k2, off, 64);
    }
    if (lane == 0) {
        sums[0] = sa; sums[1] = sb; sums[2] = k1; sums[3] = k2;
    }
}

// Fused per-layer kernel: block = one output row o.
//   ov = relu(W[o,:] . inp + b[o])            (block-wide dot reduce)
//   outp[o] = ov
//   nW[o,i] = 0.5*(lin_i + sum_m |q_m|*V2[m]) + bm2
//     q_m   = inp_i*A[m] + W[o,i]*B[m] + P[m],  P[m] = bm1[m] + ov*C[m]
//     lin_i = inp_i*SA + W[o,i]*SB + SP,        SP   = K1 + ov*K2
// Inner loop = 3 VALU per (elem, m): fma, fma, fma(abs) — |q| is a free
// VOP3 modifier. P pinned in VGPR so each fma has at most one SGPR operand.
__global__ __launch_bounds__(256) void fused_k(const float* __restrict__ W,
                                               const float* __restrict__ b,
                                               const float* __restrict__ inp,
                                               float* __restrict__ outp,
                                               const float* __restrict__ Wm1,
                                               const float* __restrict__ bm1,
                                               const float* __restrict__ Wm2,
                                               const float* __restrict__ bm2,
                                               const float* __restrict__ sums,
                                               float* __restrict__ nWl) {
    const int row  = blockIdx.x;
    const int wave = threadIdx.x >> 6;
    const int lane = threadIdx.x & 63;

    const float* Wr  = W   + (size_t)row * DD;
    float*       nWr = nWl + (size_t)row * DD;

    const int col0 = threadIdx.x * 4;             // first half, coalesced float4
    const int col1 = (DD / 2) + threadIdx.x * 4;  // second half
    const float4 w4a = *reinterpret_cast<const float4*>(Wr + col0);
    const float4 u4a = *reinterpret_cast<const float4*>(inp + col0);
    const float4 w4b = *reinterpret_cast<const float4*>(Wr + col1);
    const float4 u4b = *reinterpret_cast<const float4*>(inp + col1);

    // ---- block-wide dot product: W[row,:] . inp ----
    float d = 0.f;
    d = fmaf(w4a.x, u4a.x, d); d = fmaf(w4a.y, u4a.y, d);
    d = fmaf(w4a.z, u4a.z, d); d = fmaf(w4a.w, u4a.w, d);
    d = fmaf(w4b.x, u4b.x, d); d = fmaf(w4b.y, u4b.y, d);
    d = fmaf(w4b.z, u4b.z, d); d = fmaf(w4b.w, u4b.w, d);
#pragma unroll
    for (int off = 32; off > 0; off >>= 1)
        d += __shfl_down(d, off, 64);
    __shared__ float red[4];
    if (lane == 0) red[wave] = d;
    __syncthreads();
    const float ov = fmaxf((red[0] + red[1] + red[2] + red[3]) + b[row], 0.f);
    if (threadIdx.x == 0) outp[row] = ov;

    // ---- meta constants ----
    float A[MHH], B[MHH], P[MHH], V2[MHH];
#pragma unroll
    for (int m = 0; m < MHH; ++m) {
        A[m]  = Wm1[m];                 // Wm1[0,m]
        B[m]  = Wm1[MHH + m];           // Wm1[1,m]
        V2[m] = Wm2[m];
        P[m]  = fmaf(ov, Wm1[2 * MHH + m], bm1[m]);
        asm volatile("" : "+v"(P[m])); // keep P in VGPR (pairs with SGPR A/B)
    }
    const float SA = sums[0], SB = sums[1];
    const float SP = fmaf(ov, sums[3], sums[2]);
    const float bias2 = bm2[0];

    // linear parts
    float l0 = fmaf(u4a.x, SA, SP), l1 = fmaf(u4a.y, SA, SP);
    float l2 = fmaf(u4a.z, SA, SP), l3 = fmaf(u4a.w, SA, SP);
    float l4 = fmaf(u4b.x, SA, SP), l5 = fmaf(u4b.y, SA, SP);
    float l6 = fmaf(u4b.z, SA, SP), l7 = fmaf(u4b.w, SA, SP);
    l0 = fmaf(w4a.x, SB, l0); l1 = fmaf(w4a.y, SB, l1);
    l2 = fmaf(w4a.z, SB, l2); l3 = fmaf(w4a.w, SB, l3);
    l4 = fmaf(w4b.x, SB, l4); l5 = fmaf(w4b.y, SB, l5);
    l6 = fmaf(w4b.z, SB, l6); l7 = fmaf(w4b.w, SB, l7);

    // abs parts: c_e = sum_m |q_m| * V2[m]
    float c0 = 0.f, c1 = 0.f, c2 = 0.f, c3 = 0.f;
    float c4 = 0.f, c5 = 0.f, c6 = 0.f, c7 = 0.f;
#pragma unroll
    for (int m = 0; m < MHH; ++m) {
        float t0 = fmaf(u4a.x, A[m], P[m]);
        float t1 = fmaf(u4a.y, A[m], P[m]);
        float t2 = fmaf(u4a.z, A[m], P[m]);
        float t3 = fmaf(u4a.w, A[m], P[m]);
        float t4 = fmaf(u4b.x, A[m], P[m]);
        float t5 = fmaf(u4b.y, A[m], P[m]);
        float t6 = fmaf(u4b.z, A[m], P[m]);
        float t7 = fmaf(u4b.w, A[m], P[m]);
        t0 = fmaf(w4a.x, B[m], t0);
        t1 = fmaf(w4a.y, B[m], t1);
        t2 = fmaf(w4a.z, B[m], t2);
        t3 = fmaf(w4a.w, B[m], t3);
        t4 = fmaf(w4b.x, B[m], t4);
        t5 = fmaf(w4b.y, B[m], t5);
        t6 = fmaf(w4b.z, B[m], t6);
        t7 = fmaf(w4b.w, B[m], t7);
        c0 = fmaf(__builtin_fabsf(t0), V2[m], c0);
        c1 = fmaf(__builtin_fabsf(t1), V2[m], c1);
        c2 = fmaf(__builtin_fabsf(t2), V2[m], c2);
        c3 = fmaf(__builtin_fabsf(t3), V2[m], c3);
        c4 = fmaf(__builtin_fabsf(t4), V2[m], c4);
        c5 = fmaf(__builtin_fabsf(t5), V2[m], c5);
        c6 = fmaf(__builtin_fabsf(t6), V2[m], c6);
        c7 = fmaf(__builtin_fabsf(t7), V2[m], c7);
    }

    float4 r0, r1;
    r0.x = fmaf(0.5f, l0 + c0, bias2);
    r0.y = fmaf(0.5f, l1 + c1, bias2);
    r0.z = fmaf(0.5f, l2 + c2, bias2);
    r0.w = fmaf(0.5f, l3 + c3, bias2);
    r1.x = fmaf(0.5f, l4 + c4, bias2);
    r1.y = fmaf(0.5f, l5 + c5, bias2);
    r1.z = fmaf(0.5f, l6 + c6, bias2);
    r1.w = fmaf(0.5f, l7 + c7, bias2);
    *reinterpret_cast<float4*>(nWr + col0) = r0;
    *reinterpret_cast<float4*>(nWr + col1) = r1;
}

extern "C" void kernel_launch(void* const* d_in, const int* in_sizes, int n_in,
                              void* d_out, int out_size, void* d_ws, size_t ws_size,
                              hipStream_t stream) {
    const float* x   = (const float*)d_in[0];
    const float* W1  = (const float*)d_in[1];
    const float* b1  = (const float*)d_in[2];
    const float* W2  = (const float*)d_in[3];
    const float* b2  = (const float*)d_in[4];
    const float* W3  = (const float*)d_in[5];
    const float* b3  = (const float*)d_in[6];
    const float* Wm1 = (const float*)d_in[7];
    const float* bm1 = (const float*)d_in[8];
    const float* Wm2 = (const float*)d_in[9];
    const float* bm2 = (const float*)d_in[10];

    float* out = (float*)d_out;            // out: [2048]
    float* nW  = out + DD;                 // nW1|nW2|nW3: 3 x 2048 x 2048
    float* a1   = (float*)d_ws;            // [2048]
    float* a2   = a1 + DD;                 // [2048]
    float* sums = a2 + DD;                 // [4]

    prep_k<<<1, 64, 0, stream>>>(Wm1, bm1, Wm2, sums);
    fused_k<<<DD, 256, 0, stream>>>(W1, b1, x,  a1,  Wm1, bm1, Wm2, bm2, sums, nW);
    fused_k<<<DD, 256, 0, stream>>>(W2, b2, a1, a2,  Wm1, bm1, Wm2, bm2, sums, nW + (size_t)DD * DD);
    fused_k<<<DD, 256, 0, stream>>>(W3, b3, a2, out, Wm1, bm1, Wm2, bm2, sums, nW + 2 * (size_t)DD * DD);
}

// Round 4
// 62.111 us; speedup vs baseline: 1.0795x; 1.0795x over previous
//
#include <hip/hip_runtime.h>

#define DD 2048
#define MHH 32

// Blocks 0..DD/4-1: y[row] = relu(dot(W[row,:], x) + b[row]), one wave per row.
// Block DD/4 (last): computes the meta-linear collapse sums:
//   sums = { SA = sum A*V2, SB = sum B*V2, K1 = sum bm1*V2, K2 = sum C*V2 }.
__global__ __launch_bounds__(256) void gemv_relu_prep_k(const float* __restrict__ W,
                                                        const float* __restrict__ x,
                                                        const float* __restrict__ b,
                                                        float* __restrict__ y,
                                                        const float* __restrict__ Wm1,
                                                        const float* __restrict__ bm1,
                                                        const float* __restrict__ Wm2,
                                                        float* __restrict__ sums) {
    if (blockIdx.x == DD / 4) {
        if (threadIdx.x >= 64) return;
        const int lane = threadIdx.x;          // lanes 0..31 carry data
        float sa = 0.f, sb = 0.f, k1 = 0.f, k2 = 0.f;
        if (lane < MHH) {
            const float v2 = Wm2[lane];
            sa = Wm1[lane] * v2;
            sb = Wm1[MHH + lane] * v2;
            k2 = Wm1[2 * MHH + lane] * v2;
            k1 = bm1[lane] * v2;
        }
#pragma unroll
        for (int off = 16; off > 0; off >>= 1) {
            sa += __shfl_down(sa, off, 64);
            sb += __shfl_down(sb, off, 64);
            k1 += __shfl_down(k1, off, 64);
            k2 += __shfl_down(k2, off, 64);
        }
        if (lane == 0) {
            sums[0] = sa; sums[1] = sb; sums[2] = k1; sums[3] = k2;
        }
        return;
    }
    const int wave = threadIdx.x >> 6;
    const int lane = threadIdx.x & 63;
    const int row  = (blockIdx.x << 2) + wave;
    const float* Wr = W + (size_t)row * DD;
    float acc = 0.f;
#pragma unroll
    for (int it = 0; it < 8; ++it) {
        const int col = ((it << 6) + lane) << 2;       // float4 index, coalesced
        const float4 w4 = *reinterpret_cast<const float4*>(Wr + col);
        const float4 x4 = *reinterpret_cast<const float4*>(x + col);
        acc = fmaf(w4.x, x4.x, acc);
        acc = fmaf(w4.y, x4.y, acc);
        acc = fmaf(w4.z, x4.z, acc);
        acc = fmaf(w4.w, x4.w, acc);
    }
#pragma unroll
    for (int off = 32; off > 0; off >>= 1)
        acc += __shfl_down(acc, off, 64);
    if (lane == 0) {
        const float v = acc + b[row];
        y[row] = fmaxf(v, 0.f);
    }
}

// Plain gemv+relu for layers 2 and 3.
__global__ __launch_bounds__(256) void gemv_relu_k(const float* __restrict__ W,
                                                   const float* __restrict__ x,
                                                   const float* __restrict__ b,
                                                   float* __restrict__ y) {
    const int wave = threadIdx.x >> 6;
    const int lane = threadIdx.x & 63;
    const int row  = (blockIdx.x << 2) + wave;
    const float* Wr = W + (size_t)row * DD;
    float acc = 0.f;
#pragma unroll
    for (int it = 0; it < 8; ++it) {
        const int col = ((it << 6) + lane) << 2;
        const float4 w4 = *reinterpret_cast<const float4*>(Wr + col);
        const float4 x4 = *reinterpret_cast<const float4*>(x + col);
        acc = fmaf(w4.x, x4.x, acc);
        acc = fmaf(w4.y, x4.y, acc);
        acc = fmaf(w4.z, x4.z, acc);
        acc = fmaf(w4.w, x4.w, acc);
    }
#pragma unroll
    for (int off = 32; off > 0; off >>= 1)
        acc += __shfl_down(acc, off, 64);
    if (lane == 0) {
        const float v = acc + b[row];
        y[row] = fmaxf(v, 0.f);
    }
}

// nW[o,i] = bm2 + sum_m V2[m]*relu(q_m),  q_m = inp_i*A[m] + W[o,i]*B[m] + P[m]
// Using relu(q) = 0.5*(q + |q|):
//   nW[o,i] = bm2 + 0.5*(lin_i + sum_m |q_m|*V2[m])
//   lin_i   = inp_i*SA + W[o,i]*SB + SP,  SP = K1 + ov*K2   (precomputed sums)
// Inner loop = 3 VALU per (elem, m): v_fma(u,A,P), v_fmac(w,B), v_fmac(|t|,V2).
// P pinned to VGPR so every op has at most one SGPR operand.
__global__ __launch_bounds__(256) void meta_k(const float* __restrict__ W1,
                                              const float* __restrict__ W2,
                                              const float* __restrict__ W3,
                                              const float* __restrict__ a0,
                                              const float* __restrict__ a1,
                                              const float* __restrict__ a2,
                                              const float* __restrict__ a3,
                                              const float* __restrict__ Wm1,
                                              const float* __restrict__ bm1,
                                              const float* __restrict__ Wm2,
                                              const float* __restrict__ bm2,
                                              const float* __restrict__ sums,
                                              float* __restrict__ nW) {
    const int layer = blockIdx.x >> 11;          // 2048 rows per layer
    const int row   = blockIdx.x & (DD - 1);

    const float* W   = (layer == 0) ? W1 : (layer == 1) ? W2 : W3;
    const float* inp = (layer == 0) ? a0 : (layer == 1) ? a1 : a2;
    const float* oup = (layer == 0) ? a1 : (layer == 1) ? a2 : a3;

    const float* Wr  = W  + (size_t)row * DD;
    float*       nWr = nW + (size_t)layer * DD * DD + (size_t)row * DD;

    // Hoist all global loads before the compute block.
    const int col0 = threadIdx.x * 4;            // first half, coalesced float4
    const int col1 = (DD / 2) + threadIdx.x * 4; // second half
    const float4 w4a = *reinterpret_cast<const float4*>(Wr + col0);
    const float4 u4a = *reinterpret_cast<const float4*>(inp + col0);
    const float4 w4b = *reinterpret_cast<const float4*>(Wr + col1);
    const float4 u4b = *reinterpret_cast<const float4*>(inp + col1);

    const float ov = oup[row];

    float A[MHH], B[MHH], P[MHH], V2[MHH];
#pragma unroll
    for (int m = 0; m < MHH; ++m) {
        A[m]  = Wm1[m];                 // Wm1[0,m]
        B[m]  = Wm1[MHH + m];           // Wm1[1,m]
        V2[m] = Wm2[m];
        P[m]  = fmaf(ov, Wm1[2 * MHH + m], bm1[m]);
        asm volatile("" : "+v"(P[m])); // keep P in VGPR (pairs with SGPR A/B)
    }
    const float SA = sums[0], SB = sums[1];
    const float SP = fmaf(ov, sums[3], sums[2]);
    const float bias2 = bm2[0];

    // Linear half: lin_e = u*SA + w*SB + SP.
    float l0 = fmaf(u4a.x, SA, SP), l1 = fmaf(u4a.y, SA, SP);
    float l2 = fmaf(u4a.z, SA, SP), l3 = fmaf(u4a.w, SA, SP);
    float l4 = fmaf(u4b.x, SA, SP), l5 = fmaf(u4b.y, SA, SP);
    float l6 = fmaf(u4b.z, SA, SP), l7 = fmaf(u4b.w, SA, SP);
    l0 = fmaf(w4a.x, SB, l0); l1 = fmaf(w4a.y, SB, l1);
    l2 = fmaf(w4a.z, SB, l2); l3 = fmaf(w4a.w, SB, l3);
    l4 = fmaf(w4b.x, SB, l4); l5 = fmaf(w4b.y, SB, l5);
    l6 = fmaf(w4b.z, SB, l6); l7 = fmaf(w4b.w, SB, l7);

    // Abs half: c_e = sum_m |q_m| * V2[m].
    float c0 = 0.f, c1 = 0.f, c2 = 0.f, c3 = 0.f;
    float c4 = 0.f, c5 = 0.f, c6 = 0.f, c7 = 0.f;
#pragma unroll
    for (int m = 0; m < MHH; ++m) {
        float t0 = fmaf(u4a.x, A[m], P[m]);
        float t1 = fmaf(u4a.y, A[m], P[m]);
        float t2 = fmaf(u4a.z, A[m], P[m]);
        float t3 = fmaf(u4a.w, A[m], P[m]);
        float t4 = fmaf(u4b.x, A[m], P[m]);
        float t5 = fmaf(u4b.y, A[m], P[m]);
        float t6 = fmaf(u4b.z, A[m], P[m]);
        float t7 = fmaf(u4b.w, A[m], P[m]);
        t0 = fmaf(w4a.x, B[m], t0);
        t1 = fmaf(w4a.y, B[m], t1);
        t2 = fmaf(w4a.z, B[m], t2);
        t3 = fmaf(w4a.w, B[m], t3);
        t4 = fmaf(w4b.x, B[m], t4);
        t5 = fmaf(w4b.y, B[m], t5);
        t6 = fmaf(w4b.z, B[m], t6);
        t7 = fmaf(w4b.w, B[m], t7);
        c0 = fmaf(__builtin_fabsf(t0), V2[m], c0);
        c1 = fmaf(__builtin_fabsf(t1), V2[m], c1);
        c2 = fmaf(__builtin_fabsf(t2), V2[m], c2);
        c3 = fmaf(__builtin_fabsf(t3), V2[m], c3);
        c4 = fmaf(__builtin_fabsf(t4), V2[m], c4);
        c5 = fmaf(__builtin_fabsf(t5), V2[m], c5);
        c6 = fmaf(__builtin_fabsf(t6), V2[m], c6);
        c7 = fmaf(__builtin_fabsf(t7), V2[m], c7);
    }

    float4 r0, r1;
    r0.x = fmaf(0.5f, l0 + c0, bias2);
    r0.y = fmaf(0.5f, l1 + c1, bias2);
    r0.z = fmaf(0.5f, l2 + c2, bias2);
    r0.w = fmaf(0.5f, l3 + c3, bias2);
    r1.x = fmaf(0.5f, l4 + c4, bias2);
    r1.y = fmaf(0.5f, l5 + c5, bias2);
    r1.z = fmaf(0.5f, l6 + c6, bias2);
    r1.w = fmaf(0.5f, l7 + c7, bias2);
    *reinterpret_cast<float4*>(nWr + col0) = r0;
    *reinterpret_cast<float4*>(nWr + col1) = r1;
}

extern "C" void kernel_launch(void* const* d_in, const int* in_sizes, int n_in,
                              void* d_out, int out_size, void* d_ws, size_t ws_size,
                              hipStream_t stream) {
    const float* x   = (const float*)d_in[0];
    const float* W1  = (const float*)d_in[1];
    const float* b1  = (const float*)d_in[2];
    const float* W2  = (const float*)d_in[3];
    const float* b2  = (const float*)d_in[4];
    const float* W3  = (const float*)d_in[5];
    const float* b3  = (const float*)d_in[6];
    const float* Wm1 = (const float*)d_in[7];
    const float* bm1 = (const float*)d_in[8];
    const float* Wm2 = (const float*)d_in[9];
    const float* bm2 = (const float*)d_in[10];

    float* out  = (float*)d_out;           // out: [2048]
    float* nW   = out + DD;                // nW1|nW2|nW3: 3 x 2048 x 2048
    float* a1   = (float*)d_ws;            // [2048]
    float* a2   = a1 + DD;                 // [2048]
    float* sums = a2 + DD;                 // [4]

    gemv_relu_prep_k<<<DD / 4 + 1, 256, 0, stream>>>(W1, x, b1, a1, Wm1, bm1, Wm2, sums);
    gemv_relu_k<<<DD / 4, 256, 0, stream>>>(W2, a1, b2, a2);
    gemv_relu_k<<<DD / 4, 256, 0, stream>>>(W3, a2, b3, out);
    meta_k<<<3 * DD, 256, 0, stream>>>(W1, W2, W3, x, a1, a2, out,
                                       Wm1, bm1, Wm2, bm2, sums, nW);
}